// Round 1
// baseline (788.543 us; speedup 1.0000x reference)
//
#include <hip/hip_runtime.h>
#include <hip/hip_bf16.h>

// Problem: cos-sim GEMM. x[16384,256] f32, prototypes[10000,256] f32,
// out[16384,10000] f32 = (x @ p^T) / (|x| * |p|), norms clamped to 1e-6.
//
// Strategy: pre-convert both inputs to bf16 (RNE) + exact f32 norms, then
// m97-structure bf16 MFMA GEMM (128x128 tile, BK=64, global_load_lds w=16),
// epilogue scales by rx[i]*rp[j]. Prototypes padded to 10112 rows (79*128).

#define N_ROWS 16384
#define N_COLS 10000
#define N_COLS_PAD 10112   // 79 * 128
#define KDIM 256
#define BM 128
#define BN 128
#define BK 64
#define NT_COLS 79         // col tiles
#define NT_ROWS 128        // row tiles

typedef __attribute__((ext_vector_type(8))) __bf16 bf16x8;
typedef __attribute__((ext_vector_type(4))) float f32x4;

__device__ __forceinline__ unsigned short f2bf(float f) {
    unsigned u = __builtin_bit_cast(unsigned, f);
    u += 0x7FFFu + ((u >> 16) & 1u);   // round-to-nearest-even
    return (unsigned short)(u >> 16);
}

__device__ __forceinline__ void gload16(const void* g, void* l) {
    __builtin_amdgcn_global_load_lds(
        (const __attribute__((address_space(1))) void*)g,
        (__attribute__((address_space(3))) void*)l, 16, 0, 0);
}

// One wave per row: float4 load (16B/lane), convert to bf16, sum-of-squares
// shuffle-reduce, write 1/max(norm, eps).
__global__ __launch_bounds__(256) void prep_x_kernel(
    const float* __restrict__ x, unsigned short* __restrict__ xb,
    float* __restrict__ rx, int nrows) {
    int row = blockIdx.x * 4 + (threadIdx.x >> 6);
    int lane = threadIdx.x & 63;
    if (row >= nrows) return;
    float4 v = reinterpret_cast<const float4*>(x)[row * 64 + lane];
    ushort4 o;
    o.x = f2bf(v.x); o.y = f2bf(v.y); o.z = f2bf(v.z); o.w = f2bf(v.w);
    reinterpret_cast<ushort4*>(xb)[row * 64 + lane] = o;
    float ss = v.x * v.x + v.y * v.y + v.z * v.z + v.w * v.w;
    #pragma unroll
    for (int m = 32; m >= 1; m >>= 1) ss += __shfl_xor(ss, m);
    if (lane == 0) rx[row] = 1.0f / fmaxf(sqrtf(ss), 1e-6f);
}

__global__ __launch_bounds__(256) void prep_p_kernel(
    const float* __restrict__ p, unsigned short* __restrict__ pb,
    float* __restrict__ rp, int nreal, int npad) {
    int row = blockIdx.x * 4 + (threadIdx.x >> 6);
    int lane = threadIdx.x & 63;
    if (row >= npad) return;
    if (row < nreal) {
        float4 v = reinterpret_cast<const float4*>(p)[row * 64 + lane];
        ushort4 o;
        o.x = f2bf(v.x); o.y = f2bf(v.y); o.z = f2bf(v.z); o.w = f2bf(v.w);
        reinterpret_cast<ushort4*>(pb)[row * 64 + lane] = o;
        float ss = v.x * v.x + v.y * v.y + v.z * v.z + v.w * v.w;
        #pragma unroll
        for (int m = 32; m >= 1; m >>= 1) ss += __shfl_xor(ss, m);
        if (lane == 0) rp[row] = 1.0f / fmaxf(sqrtf(ss), 1e-6f);
    } else {
        ushort4 z; z.x = 0; z.y = 0; z.z = 0; z.w = 0;
        reinterpret_cast<ushort4*>(pb)[row * 64 + lane] = z;
        if (lane == 0) rp[row] = 1.0f;   // dead cols, never stored
    }
}

// m97-structure GEMM: 256 threads = 4 waves in 2x2, each wave 64x64 output
// (4x4 grid of 16x16x32 bf16 MFMA fragments). K=256 -> 4 K-steps of BK=64.
__global__ __launch_bounds__(256, 2) void cosgemm_kernel(
    const unsigned short* __restrict__ xb,   // [16384][256] bf16
    const unsigned short* __restrict__ pb,   // [10112][256] bf16
    const float* __restrict__ rx,            // [16384]
    const float* __restrict__ rp,            // [10112]
    float* __restrict__ out)                 // [16384][10000]
{
    __shared__ __bf16 As[BM * BK];   // 16 KB, linear (no swizzle: 2-phase -> T2 null)
    __shared__ __bf16 Bs[BN * BK];   // 16 KB

    const int tid  = threadIdx.x;
    const int lane = tid & 63;
    const int wid  = tid >> 6;
    const int wr   = wid >> 1;       // wave row 0..1
    const int wc   = wid & 1;        // wave col 0..1

    const int bx   = blockIdx.x;
    const int rt   = bx / NT_COLS;
    const int ct   = bx % NT_COLS;
    const int row0 = rt * BM;
    const int col0 = ct * BN;

    f32x4 acc[4][4];
    #pragma unroll
    for (int m = 0; m < 4; ++m)
        #pragma unroll
        for (int n = 0; n < 4; ++n)
            acc[m][n] = (f32x4){0.f, 0.f, 0.f, 0.f};

    const int la = lane & 15;
    const int lg = lane >> 4;

    for (int kt = 0; kt < KDIM / BK; ++kt) {
        // ---- stage A and B tiles: 16 KB each, 16B/lane/issue, 4 issues/wave ----
        #pragma unroll
        for (int i = 0; i < 4; ++i) {
            int e = ((i << 2) + wid) * 512 + (lane << 3);  // element idx in tile
            int r = e >> 6;                                 // tile row
            int c = e & 63;                                 // k within BK
            gload16((const void*)(xb + (size_t)(row0 + r) * KDIM + kt * BK + c),
                    (void*)(As + e));
            gload16((const void*)(pb + (size_t)(col0 + r) * KDIM + kt * BK + c),
                    (void*)(Bs + e));
        }
        __syncthreads();   // compiler emits vmcnt(0) drain here

        // ---- compute: 2 kk-chunks of K=32, 16 MFMA each ----
        #pragma unroll
        for (int kk = 0; kk < 2; ++kk) {
            const int kb = kk * 32 + lg * 8;
            bf16x8 a[4], b[4];
            #pragma unroll
            for (int m = 0; m < 4; ++m) {
                a[m] = *reinterpret_cast<const bf16x8*>(As + (wr * 64 + m * 16 + la) * BK + kb);
                b[m] = *reinterpret_cast<const bf16x8*>(Bs + (wc * 64 + m * 16 + la) * BK + kb);
            }
            #pragma unroll
            for (int m = 0; m < 4; ++m)
                #pragma unroll
                for (int n = 0; n < 4; ++n)
                    acc[m][n] = __builtin_amdgcn_mfma_f32_16x16x32_bf16(
                        a[m], b[n], acc[m][n], 0, 0, 0);
        }
        __syncthreads();
    }

    // ---- epilogue: C/D layout col=lane&15, row=(lane>>4)*4+reg (m89-verified) ----
    #pragma unroll
    for (int m = 0; m < 4; ++m) {
        const int grow_base = row0 + wr * 64 + m * 16 + lg * 4;
        float rxv[4];
        #pragma unroll
        for (int j = 0; j < 4; ++j) rxv[j] = rx[grow_base + j];
        #pragma unroll
        for (int n = 0; n < 4; ++n) {
            const int gcol = col0 + wc * 64 + n * 16 + la;
            if (gcol < N_COLS) {
                const float rpv = rp[gcol];
                #pragma unroll
                for (int j = 0; j < 4; ++j) {
                    out[(size_t)(grow_base + j) * N_COLS + gcol] =
                        acc[m][n][j] * rxv[j] * rpv;
                }
            }
        }
    }
}

extern "C" void kernel_launch(void* const* d_in, const int* in_sizes, int n_in,
                              void* d_out, int out_size, void* d_ws, size_t ws_size,
                              hipStream_t stream) {
    const float* x = (const float*)d_in[0];
    const float* p = (const float*)d_in[1];
    float* out = (float*)d_out;

    // workspace layout (13.7 MB): xb | pb | rx | rp
    unsigned short* xb = (unsigned short*)d_ws;
    unsigned short* pb = xb + (size_t)N_ROWS * KDIM;
    float* rx = (float*)(pb + (size_t)N_COLS_PAD * KDIM);
    float* rp = rx + N_ROWS;

    prep_x_kernel<<<N_ROWS / 4, 256, 0, stream>>>(x, xb, rx, N_ROWS);
    prep_p_kernel<<<N_COLS_PAD / 4, 256, 0, stream>>>(p, pb, rp, N_COLS, N_COLS_PAD);
    cosgemm_kernel<<<NT_ROWS * NT_COLS, 256, 0, stream>>>(xb, pb, rx, rp, out);
}